// Round 8
// baseline (698.639 us; speedup 1.0000x reference)
//
#include <hip/hip_runtime.h>
#include <hip/hip_bf16.h>

#define NCODES 8192
#define DIM    64
#define NROWS  65536   // 16*4096

typedef __attribute__((ext_vector_type(8))) short short8v;
typedef __attribute__((ext_vector_type(4))) float f32x4;

// ---- workspace layout (float offsets). Total 541729 f32 ~= 2.17 MB (proven to fit).
#define WS_EBIAS   0         // 8192 f32
#define WS_COUNTS  8192      // 8192 f32
#define WS_LOSSP   16384     // 1024 f32
#define WS_DW      17408     // 524288 f32  (bf16 eh aliases first 1 MB until phaseA done)
#define WS_NCSP    541696    // 32 f32
#define WS_N       541728    // 1 f32
#define WS_END     541729

#define WS_EH      WS_DW     // eh dead after phaseA; dw memset after phaseA

// cm (65536 rows x 128 chunk-max bf16, 16.78 MB) lives in d_out's OUT_ZQ region:
// block b's tile == exactly block b's z_q bytes. Phase B stages tile->LDS, syncs,
// then overwrites with z_q.

// ---- output layout (float offsets, tuple order) ----
#define OUT_ZQ     0
#define OUT_IDX    4194304
#define OUT_LOSS   4259840
#define OUT_NEMB   4259841
#define OUT_NCS    4784129
#define OUT_NEMA   4792321

// Screening margin: worst-case bf16(7-bit mantissa) dot error 2*2^-8*||z||max
// ~=0.087 per side + cm quant 0.031 -> 0.236 worst; 0.30 gives 27% headroom.
// (0.15 failed round 5; 0.30 passed round 7.)
#define CUT_MARGIN 0.30f

__device__ __forceinline__ unsigned short f2b(float f) {
    unsigned u = __float_as_uint(f);
    return (unsigned short)((u + 0x7FFFu + ((u >> 16) & 1u)) >> 16);  // RNE
}
__device__ __forceinline__ float b2f(unsigned short h) {
    return __uint_as_float(((unsigned)h) << 16);
}

// ||e_k||^2 per code (f32, used for exact scores in phase B)
__global__ void vq_ebias_kernel(const float* __restrict__ emb, float* __restrict__ ebias) {
    int k = blockIdx.x * 256 + threadIdx.x;
    const float4* e4 = reinterpret_cast<const float4*>(emb + (size_t)k * DIM);
    float s = 0.f;
#pragma unroll
    for (int i = 0; i < 16; i++) {
        float4 v = e4[i];
        s = fmaf(v.x, v.x, s); s = fmaf(v.y, v.y, s);
        s = fmaf(v.z, v.z, s); s = fmaf(v.w, v.w, s);
    }
    ebias[k] = s;
}

// emb f32 -> bf16 (row-major [code][k])
__global__ void vq_eprep_kernel(const float* __restrict__ emb, short* __restrict__ eh) {
    int i = blockIdx.x * 256 + threadIdx.x;   // per 2 elems
    float2 v = *reinterpret_cast<const float2*>(emb + (size_t)i * 2);
    unsigned o = (unsigned)f2b(v.x) | ((unsigned)f2b(v.y) << 16);
    *reinterpret_cast<unsigned*>(eh + (size_t)i * 2) = o;
}

// Phase A: bf16 MFMA screening. Per (row, 64-code chunk) store chunk-max dot (bf16).
// cm layout: [rowblk(1024)][gchunk(128)][row_in_blk(64)] ushort, in OUT_ZQ region.
// Quarter-split (r8): grid 1024 = 256 row-groups x 4 code-quarters -> 4096 waves
// (4/SIMD) for latency hiding; total L2 A-traffic is split-invariant.
__global__ __launch_bounds__(256)
void vq_phaseA(const float* __restrict__ z, const short* __restrict__ eh,
               unsigned short* __restrict__ cm)
{
    const int tid = threadIdx.x;
    const int l = tid & 63, w = tid >> 6;
    const int rg = blockIdx.x >> 2;        // 256 row-groups of 256 rows
    const int quarter = blockIdx.x & 3;    // code quarter (2048 codes each)
    const int rowbase = rg * 256 + w * 64; // this wave's 64 rows
    const int kq0 = (l >> 4) * 8;          // lane's k-offset within a K=32 step

    // Loop-invariant B-fragments (z rows, bf16-converted in-register): [rt][kstep]
    short8v B[4][2];
#pragma unroll
    for (int rt = 0; rt < 4; rt++) {
        const float* zr = z + (size_t)(rowbase + rt * 16 + (l & 15)) * 64;
#pragma unroll
        for (int s = 0; s < 2; s++) {
            int k0 = s * 32 + kq0;
            float4 p0 = *reinterpret_cast<const float4*>(zr + k0);
            float4 p1 = *reinterpret_cast<const float4*>(zr + k0 + 4);
            short8v t;
            t[0] = (short)f2b(p0.x); t[1] = (short)f2b(p0.y);
            t[2] = (short)f2b(p0.z); t[3] = (short)f2b(p0.w);
            t[4] = (short)f2b(p1.x); t[5] = (short)f2b(p1.y);
            t[6] = (short)f2b(p1.z); t[7] = (short)f2b(p1.w);
            B[rt][s] = t;
        }
    }

    unsigned short* cmw = cm + (size_t)(rowbase >> 6) * 8192;

    for (int ch = 0; ch < 32; ch++) {
        const int gchunk = quarter * 32 + ch;
        const int cbase = gchunk * 64;
        // A-fragments: 64 codes of this chunk, straight from global (L2-hot)
        short8v A[4][2];
#pragma unroll
        for (int ct = 0; ct < 4; ct++) {
            const short* ep = eh + (size_t)(cbase + ct * 16 + (l & 15)) * 64;
            A[ct][0] = *reinterpret_cast<const short8v*>(ep + kq0);
            A[ct][1] = *reinterpret_cast<const short8v*>(ep + 32 + kq0);
        }
        float runmax[4] = {-3.4e38f, -3.4e38f, -3.4e38f, -3.4e38f};
#pragma unroll
        for (int ct = 0; ct < 4; ct++) {
#pragma unroll
            for (int rt = 0; rt < 4; rt++) {
                f32x4 acc = {0.f, 0.f, 0.f, 0.f};
                acc = __builtin_amdgcn_mfma_f32_16x16x32_bf16(A[ct][0], B[rt][0], acc, 0, 0, 0);
                acc = __builtin_amdgcn_mfma_f32_16x16x32_bf16(A[ct][1], B[rt][1], acc, 0, 0, 0);
                // D col = lane&15 = z row (rt tile); D row = (lane>>4)*4+reg = code
                float m = fmaxf(fmaxf(acc[0], acc[1]), fmaxf(acc[2], acc[3]));
                runmax[rt] = fmaxf(runmax[rt], m);
            }
        }
#pragma unroll
        for (int rt = 0; rt < 4; rt++) {
            float r1 = fmaxf(runmax[rt], __shfl_xor(runmax[rt], 16));
            float r2 = fmaxf(r1, __shfl_xor(r1, 32));
            if (l < 16) cmw[(size_t)gchunk * 64 + rt * 16 + l] = f2b(r2);
        }
    }
}

// Phase B: candidate scan + exact f32 recheck + fused epilogue.
// r8: 512 threads (8 waves x 8 rows) for 32 waves/CU occupancy (was 16).
// Reads its cm tile from the OUT_ZQ region, then overwrites it with z_q.
__global__ __launch_bounds__(512)
void vq_phaseB(const float* __restrict__ z, const float* __restrict__ emb,
               const float* __restrict__ ebias, float* __restrict__ out,
               float* __restrict__ counts, float* __restrict__ dw,
               float* __restrict__ lossp)
{
    __shared__ float zlds[64 * 64];
    __shared__ unsigned short cmlds[128][68];
    __shared__ float lred[8];
    const int tid = threadIdx.x;
    const int l = tid & 63, w = tid >> 6;
    const int rowbase = blockIdx.x * 64;

    {   // stage z tile (64 rows x 64 dims f32)
        const float4* zg = reinterpret_cast<const float4*>(z + (size_t)rowbase * 64);
        for (int i = tid; i < 1024; i += 512)
            reinterpret_cast<float4*>(zlds)[i] = zg[i];
    }
    {   // stage this block's cm tile from OUT_ZQ region: [chunk][row]
        const unsigned short* g =
            reinterpret_cast<const unsigned short*>(out + OUT_ZQ) + (size_t)blockIdx.x * 8192;
#pragma unroll
        for (int p = 0; p < 2; p++) {
            int idx = tid + p * 512;                 // ushort8 index 0..1023
            uint4 v = *reinterpret_cast<const uint4*>(g + idx * 8);
            int chunk = idx >> 3, rs = (idx & 7) * 8;
            *reinterpret_cast<uint2*>(&cmlds[chunk][rs])     = make_uint2(v.x, v.y);
            *reinterpret_cast<uint2*>(&cmlds[chunk][rs + 4]) = make_uint2(v.z, v.w);
        }
    }
    __syncthreads();   // cm tile fully in LDS; safe to overwrite with z_q below

    float lacc = 0.f;
    for (int p = 0; p < 8; p++) {
        const int row = w * 8 + p;
        const int grow = rowbase + row;
        float f0 = b2f(cmlds[l][row]);
        float f1 = b2f(cmlds[l + 64][row]);
        float M = fmaxf(f0, f1);
#pragma unroll
        for (int o = 1; o < 64; o <<= 1) M = fmaxf(M, __shfl_xor(M, o));
        const float cut = M - CUT_MARGIN;
        unsigned long long m0 = __ballot(f0 >= cut);
        unsigned long long m1 = __ballot(f1 >= cut);

        float best = 3.4e38f; int bidx = 0;
        const float* zr = zlds + row * 64;
        while (m0 | m1) {   // ascending chunk order -> first-occurrence ties
            int c;
            if (m0) { c = __ffsll(m0) - 1; m0 &= m0 - 1; }
            else    { c = 64 + __ffsll(m1) - 1; m1 &= m1 - 1; }
            int code = c * 64 + l;
            const float4* ef = reinterpret_cast<const float4*>(emb + (size_t)code * 64);
            float dot = 0.f;
#pragma unroll 8
            for (int d = 0; d < 16; d++) {
                float4 e4 = ef[d];
                float4 z4 = *reinterpret_cast<const float4*>(zr + d * 4);
                dot = fmaf(e4.x, z4.x, dot); dot = fmaf(e4.y, z4.y, dot);
                dot = fmaf(e4.z, z4.z, dot); dot = fmaf(e4.w, z4.w, dot);
            }
            float s = fmaf(-2.f, dot, ebias[code]);
            if (s < best) { best = s; bidx = code; }   // strict <: earlier code wins ties
        }
#pragma unroll
        for (int o = 1; o < 64; o <<= 1) {
            float ov = __shfl_xor(best, o);
            int oi = __shfl_xor(bidx, o);
            if (ov < best || (ov == best && oi < bidx)) { best = ov; bidx = oi; }
        }
        // fused epilogue: lane = dim
        float ev = emb[(size_t)bidx * 64 + l];
        float zv = zr[l];
        out[OUT_ZQ + (size_t)grow * 64 + l] = zv + (ev - zv);
        float df = ev - zv;
        lacc = fmaf(df, df, lacc);
        atomicAdd(&dw[(size_t)bidx * 64 + l], zv);
        if (l == 0) {
            out[OUT_IDX + grow] = (float)bidx;
            atomicAdd(&counts[bidx], 1.0f);
        }
    }
#pragma unroll
    for (int o = 1; o < 64; o <<= 1) lacc += __shfl_xor(lacc, o);
    if (l == 0) lred[w] = lacc;
    __syncthreads();
    if (tid == 0) {
        float t = 0.f;
#pragma unroll
        for (int i = 0; i < 8; i++) t += lred[i];
        lossp[blockIdx.x] = t;
    }
}

// new_cluster_size + partial sums
__global__ void vq_ncs_kernel(const float* __restrict__ ema_cs, const float* __restrict__ counts,
                              float* __restrict__ out, float* __restrict__ ncsp) {
    __shared__ float r4[4];
    int k = blockIdx.x * 256 + threadIdx.x;
    float v = ema_cs[k] * 0.99f + counts[k] * 0.01f;
    out[OUT_NCS + k] = v;
    float s = v;
#pragma unroll
    for (int o = 32; o > 0; o >>= 1) s += __shfl_down(s, o, 64);
    if ((threadIdx.x & 63) == 0) r4[threadIdx.x >> 6] = s;
    __syncthreads();
    if (threadIdx.x == 0) ncsp[blockIdx.x] = (r4[0] + r4[1]) + (r4[2] + r4[3]);
}

// n = sum(ncs); vq_loss
__global__ void vq_finalize_kernel(const float* __restrict__ ncsp, const float* __restrict__ lossp,
                                   float* __restrict__ nout, float* __restrict__ out) {
    __shared__ float r4[4];
    int t = threadIdx.x;
    float ls = (lossp[t] + lossp[t + 256]) + (lossp[t + 512] + lossp[t + 768]);
#pragma unroll
    for (int o = 32; o > 0; o >>= 1) ls += __shfl_down(ls, o, 64);
    if ((t & 63) == 0) r4[t >> 6] = ls;
    __syncthreads();
    if (t == 0) {
        float total = (r4[0] + r4[1]) + (r4[2] + r4[3]);
        out[OUT_LOSS] = 0.25f * (total * (1.0f / 4194304.0f));
    }
    if (t < 64) {
        float nv = (t < 32) ? ncsp[t] : 0.f;
#pragma unroll
        for (int o = 32; o > 0; o >>= 1) nv += __shfl_down(nv, o, 64);
        if (t == 0) nout[0] = nv;
    }
}

// new_ema_embedding + new_embedding
__global__ void vq_embupd_kernel(const float* __restrict__ ema_emb, const float* __restrict__ dw,
                                 const float* __restrict__ ncs_out, const float* __restrict__ nptr,
                                 float* __restrict__ out) {
    int i = blockIdx.x * 256 + threadIdx.x;
    int k = i >> 6;
    float nev = ema_emb[i] * 0.99f + dw[i] * 0.01f;
    out[OUT_NEMA + i] = nev;
    float n = nptr[0];
    float ncs = ncs_out[k];
    float cs = (ncs + 1e-5f) / (n + 8192.0f * 1e-5f) * n;
    out[OUT_NEMB + i] = nev / cs;
}

extern "C" void kernel_launch(void* const* d_in, const int* in_sizes, int n_in,
                              void* d_out, int out_size, void* d_ws, size_t ws_size,
                              hipStream_t stream) {
    (void)in_sizes; (void)n_in; (void)out_size; (void)ws_size;
    const float* z       = (const float*)d_in[0];
    const float* emb     = (const float*)d_in[1];
    const float* ema_cs  = (const float*)d_in[2];
    const float* ema_emb = (const float*)d_in[3];
    float* out = (float*)d_out;
    float* ws  = (float*)d_ws;

    short* eh          = (short*)(ws + WS_EH);                     // aliases dw region
    unsigned short* cm = (unsigned short*)(out + OUT_ZQ);          // aliases z_q region

    vq_ebias_kernel<<<NCODES / 256, 256, 0, stream>>>(emb, ws + WS_EBIAS);
    vq_eprep_kernel<<<(NCODES * DIM / 2) / 256, 256, 0, stream>>>(emb, eh);
    vq_phaseA<<<1024, 256, 0, stream>>>(z, eh, cm);
    // eh dead now; zero counts + lossp + dw (one contiguous range) before phase B
    hipMemsetAsync(ws + WS_COUNTS, 0,
                   (size_t)(WS_DW + NCODES * DIM - WS_COUNTS) * sizeof(float), stream);
    vq_phaseB<<<1024, 512, 0, stream>>>(z, emb, ws + WS_EBIAS,
                                        out, ws + WS_COUNTS, ws + WS_DW, ws + WS_LOSSP);
    vq_ncs_kernel<<<NCODES / 256, 256, 0, stream>>>(ema_cs, ws + WS_COUNTS, out, ws + WS_NCSP);
    vq_finalize_kernel<<<1, 256, 0, stream>>>(ws + WS_NCSP, ws + WS_LOSSP, ws + WS_N, out);
    vq_embupd_kernel<<<(NCODES * DIM) / 256, 256, 0, stream>>>(ema_emb, ws + WS_DW,
                                                               out + OUT_NCS, ws + WS_N, out);
}

// Round 9
// 621.166 us; speedup vs baseline: 1.1247x; 1.1247x over previous
//
#include <hip/hip_runtime.h>
#include <hip/hip_bf16.h>

#define NCODES 8192
#define DIM    64
#define NROWS  65536   // 16*4096

typedef __attribute__((ext_vector_type(8))) short short8v;
typedef __attribute__((ext_vector_type(4))) float f32x4;

// ---- workspace layout (float offsets). Total 541729 f32 ~= 2.17 MB (proven to fit).
#define WS_EBIAS   0         // 8192 f32
#define WS_COUNTS  8192      // 8192 f32
#define WS_LOSSP   16384     // 1024 f32
#define WS_DW      17408     // 524288 f32  (bf16 eh aliases first 1 MB until phaseA done)
#define WS_NCSP    541696    // 32 f32
#define WS_N       541728    // 1 f32
#define WS_END     541729

#define WS_EH      WS_DW     // eh dead after phaseA; dw memset after phaseA

// cm (65536 rows x 128 chunk-max bf16, 16.78 MB) lives in d_out's OUT_ZQ region:
// block b's tile == exactly block b's z_q bytes. Phase B stages tile->LDS, syncs,
// then overwrites with z_q.

// ---- output layout (float offsets, tuple order) ----
#define OUT_ZQ     0
#define OUT_IDX    4194304
#define OUT_LOSS   4259840
#define OUT_NEMB   4259841
#define OUT_NCS    4784129
#define OUT_NEMA   4792321

// Screening margin: worst-case bf16(7-bit mantissa) dot error 2*2^-8*||z||max
// ~=0.087 per side + cm quant 0.031 -> 0.236 worst; 0.30 gives 27% headroom.
// (0.15 failed round 5; 0.30 passed rounds 7/8.)
#define CUT_MARGIN 0.30f

__device__ __forceinline__ unsigned short f2b(float f) {
    unsigned u = __float_as_uint(f);
    return (unsigned short)((u + 0x7FFFu + ((u >> 16) & 1u)) >> 16);  // RNE
}
__device__ __forceinline__ float b2f(unsigned short h) {
    return __uint_as_float(((unsigned)h) << 16);
}

// ||e_k||^2 per code (f32, used for exact scores in phase B)
__global__ void vq_ebias_kernel(const float* __restrict__ emb, float* __restrict__ ebias) {
    int k = blockIdx.x * 256 + threadIdx.x;
    const float4* e4 = reinterpret_cast<const float4*>(emb + (size_t)k * DIM);
    float s = 0.f;
#pragma unroll
    for (int i = 0; i < 16; i++) {
        float4 v = e4[i];
        s = fmaf(v.x, v.x, s); s = fmaf(v.y, v.y, s);
        s = fmaf(v.z, v.z, s); s = fmaf(v.w, v.w, s);
    }
    ebias[k] = s;
}

// emb f32 -> bf16 (row-major [code][k])
__global__ void vq_eprep_kernel(const float* __restrict__ emb, short* __restrict__ eh) {
    int i = blockIdx.x * 256 + threadIdx.x;   // per 2 elems
    float2 v = *reinterpret_cast<const float2*>(emb + (size_t)i * 2);
    unsigned o = (unsigned)f2b(v.x) | ((unsigned)f2b(v.y) << 16);
    *reinterpret_cast<unsigned*>(eh + (size_t)i * 2) = o;
}

// Phase A: bf16 MFMA screening. Per (row, 64-code chunk) store chunk-max dot (bf16).
// cm layout: [rowblk(1024)][gchunk(128)][row_in_blk(64)] ushort, in OUT_ZQ region.
__global__ __launch_bounds__(256)
void vq_phaseA(const float* __restrict__ z, const short* __restrict__ eh,
               unsigned short* __restrict__ cm)
{
    const int tid = threadIdx.x;
    const int l = tid & 63, w = tid >> 6;
    const int rg = blockIdx.x >> 2;        // 256 row-groups of 256 rows
    const int quarter = blockIdx.x & 3;    // code quarter (2048 codes each)
    const int rowbase = rg * 256 + w * 64; // this wave's 64 rows
    const int kq0 = (l >> 4) * 8;          // lane's k-offset within a K=32 step

    // Loop-invariant B-fragments (z rows, bf16-converted in-register): [rt][kstep]
    short8v B[4][2];
#pragma unroll
    for (int rt = 0; rt < 4; rt++) {
        const float* zr = z + (size_t)(rowbase + rt * 16 + (l & 15)) * 64;
#pragma unroll
        for (int s = 0; s < 2; s++) {
            int k0 = s * 32 + kq0;
            float4 p0 = *reinterpret_cast<const float4*>(zr + k0);
            float4 p1 = *reinterpret_cast<const float4*>(zr + k0 + 4);
            short8v t;
            t[0] = (short)f2b(p0.x); t[1] = (short)f2b(p0.y);
            t[2] = (short)f2b(p0.z); t[3] = (short)f2b(p0.w);
            t[4] = (short)f2b(p1.x); t[5] = (short)f2b(p1.y);
            t[6] = (short)f2b(p1.z); t[7] = (short)f2b(p1.w);
            B[rt][s] = t;
        }
    }

    unsigned short* cmw = cm + (size_t)(rowbase >> 6) * 8192;

    for (int ch = 0; ch < 32; ch++) {
        const int gchunk = quarter * 32 + ch;
        const int cbase = gchunk * 64;
        // A-fragments: 64 codes of this chunk, straight from global (L2-hot)
        short8v A[4][2];
#pragma unroll
        for (int ct = 0; ct < 4; ct++) {
            const short* ep = eh + (size_t)(cbase + ct * 16 + (l & 15)) * 64;
            A[ct][0] = *reinterpret_cast<const short8v*>(ep + kq0);
            A[ct][1] = *reinterpret_cast<const short8v*>(ep + 32 + kq0);
        }
        float runmax[4] = {-3.4e38f, -3.4e38f, -3.4e38f, -3.4e38f};
#pragma unroll
        for (int ct = 0; ct < 4; ct++) {
#pragma unroll
            for (int rt = 0; rt < 4; rt++) {
                f32x4 acc = {0.f, 0.f, 0.f, 0.f};
                acc = __builtin_amdgcn_mfma_f32_16x16x32_bf16(A[ct][0], B[rt][0], acc, 0, 0, 0);
                acc = __builtin_amdgcn_mfma_f32_16x16x32_bf16(A[ct][1], B[rt][1], acc, 0, 0, 0);
                // D col = lane&15 = z row (rt tile); D row = (lane>>4)*4+reg = code
                float m = fmaxf(fmaxf(acc[0], acc[1]), fmaxf(acc[2], acc[3]));
                runmax[rt] = fmaxf(runmax[rt], m);
            }
        }
#pragma unroll
        for (int rt = 0; rt < 4; rt++) {
            float r1 = fmaxf(runmax[rt], __shfl_xor(runmax[rt], 16));
            float r2 = fmaxf(r1, __shfl_xor(r1, 32));
            if (l < 16) cmw[(size_t)gchunk * 64 + rt * 16 + l] = f2b(r2);
        }
    }
}

// Phase B v2: COALESCED candidate recheck.
// r9: lane = (code-quad cg = l>>4, dim-quad dq = l&15). One wave load covers 4
// consecutive emb rows = 1KB contiguous = 8 cache lines/inst (was: lane=code ->
// 64 lines/inst, which saturated the per-CU TA pipe at 8% VALU / flat-vs-occupancy).
// Dot = 4-dim partial + 4-step shfl_xor butterfly over the 16 dq lanes (butterfly
// yields bit-identical sums in all 16 lanes -> final argmin needs only 2
// lexicographic steps across cg). Tie semantics identical to rounds 7/8.
__global__ __launch_bounds__(512, 4)
void vq_phaseB(const float* __restrict__ z, const float* __restrict__ emb,
               const float* __restrict__ ebias, float* __restrict__ out,
               float* __restrict__ counts, float* __restrict__ dw,
               float* __restrict__ lossp)
{
    __shared__ float zlds[64 * 64];
    __shared__ unsigned short cmlds[128][68];
    __shared__ float lred[8];
    const int tid = threadIdx.x;
    const int l = tid & 63, w = tid >> 6;
    const int rowbase = blockIdx.x * 64;

    {   // stage z tile (64 rows x 64 dims f32)
        const float4* zg = reinterpret_cast<const float4*>(z + (size_t)rowbase * 64);
        for (int i = tid; i < 1024; i += 512)
            reinterpret_cast<float4*>(zlds)[i] = zg[i];
    }
    {   // stage this block's cm tile from OUT_ZQ region: [chunk][row]
        const unsigned short* g =
            reinterpret_cast<const unsigned short*>(out + OUT_ZQ) + (size_t)blockIdx.x * 8192;
#pragma unroll
        for (int p = 0; p < 2; p++) {
            int idx = tid + p * 512;                 // ushort8 index 0..1023
            uint4 v = *reinterpret_cast<const uint4*>(g + idx * 8);
            int chunk = idx >> 3, rs = (idx & 7) * 8;
            *reinterpret_cast<uint2*>(&cmlds[chunk][rs])     = make_uint2(v.x, v.y);
            *reinterpret_cast<uint2*>(&cmlds[chunk][rs + 4]) = make_uint2(v.z, v.w);
        }
    }
    __syncthreads();   // cm tile fully in LDS; safe to overwrite with z_q below

    const int cg = l >> 4;   // code sub-group within chunk (0..3)
    const int dq = l & 15;   // dim quad (0..15)

    float lacc = 0.f;
    for (int p = 0; p < 8; p++) {
        const int row = w * 8 + p;
        const int grow = rowbase + row;
        float f0 = b2f(cmlds[l][row]);
        float f1 = b2f(cmlds[l + 64][row]);
        float M = fmaxf(f0, f1);
#pragma unroll
        for (int o = 1; o < 64; o <<= 1) M = fmaxf(M, __shfl_xor(M, o));
        const float cut = M - CUT_MARGIN;
        unsigned long long m0 = __ballot(f0 >= cut);
        unsigned long long m1 = __ballot(f1 >= cut);

        // lane's dim-quad of this z row (reused across all candidates)
        const float4 zq = *reinterpret_cast<const float4*>(zlds + row * 64 + dq * 4);

        float best = 3.4e38f; int bidx = 0;
        while (m0 | m1) {   // ascending chunk order -> first-occurrence ties
            int c;
            if (m0) { c = __ffsll(m0) - 1; m0 &= m0 - 1; }
            else    { c = 64 + __ffsll(m1) - 1; m1 &= m1 - 1; }
            const int cbase = c * 64;
#pragma unroll
            for (int g = 0; g < 16; g++) {
                const int code = cbase + g * 4 + cg;
                float4 ef = *reinterpret_cast<const float4*>(emb + (size_t)code * 64 + dq * 4);
                float d4 = ef.x * zq.x;
                d4 = fmaf(ef.y, zq.y, d4);
                d4 = fmaf(ef.z, zq.z, d4);
                d4 = fmaf(ef.w, zq.w, d4);
                // butterfly over the 16 dq lanes -> full dot in every lane
                d4 += __shfl_xor(d4, 1);
                d4 += __shfl_xor(d4, 2);
                d4 += __shfl_xor(d4, 4);
                d4 += __shfl_xor(d4, 8);
                float s = fmaf(-2.f, d4, ebias[code]);
                if (s < best) { best = s; bidx = code; }  // strict <: earlier code wins
            }
        }
        // dq lanes are bit-identical -> argmin only across cg (xor 16, 32)
#pragma unroll
        for (int o = 16; o < 64; o <<= 1) {
            float ov = __shfl_xor(best, o);
            int oi = __shfl_xor(bidx, o);
            if (ov < best || (ov == best && oi < bidx)) { best = ov; bidx = oi; }
        }
        // fused epilogue: lane = dim
        float ev = emb[(size_t)bidx * 64 + l];
        float zv = zlds[row * 64 + l];
        out[OUT_ZQ + (size_t)grow * 64 + l] = zv + (ev - zv);
        float df = ev - zv;
        lacc = fmaf(df, df, lacc);
        atomicAdd(&dw[(size_t)bidx * 64 + l], zv);
        if (l == 0) {
            out[OUT_IDX + grow] = (float)bidx;
            atomicAdd(&counts[bidx], 1.0f);
        }
    }
#pragma unroll
    for (int o = 1; o < 64; o <<= 1) lacc += __shfl_xor(lacc, o);
    if (l == 0) lred[w] = lacc;
    __syncthreads();
    if (tid == 0) {
        float t = 0.f;
#pragma unroll
        for (int i = 0; i < 8; i++) t += lred[i];
        lossp[blockIdx.x] = t;
    }
}

// new_cluster_size + partial sums
__global__ void vq_ncs_kernel(const float* __restrict__ ema_cs, const float* __restrict__ counts,
                              float* __restrict__ out, float* __restrict__ ncsp) {
    __shared__ float r4[4];
    int k = blockIdx.x * 256 + threadIdx.x;
    float v = ema_cs[k] * 0.99f + counts[k] * 0.01f;
    out[OUT_NCS + k] = v;
    float s = v;
#pragma unroll
    for (int o = 32; o > 0; o >>= 1) s += __shfl_down(s, o, 64);
    if ((threadIdx.x & 63) == 0) r4[threadIdx.x >> 6] = s;
    __syncthreads();
    if (threadIdx.x == 0) ncsp[blockIdx.x] = (r4[0] + r4[1]) + (r4[2] + r4[3]);
}

// n = sum(ncs); vq_loss
__global__ void vq_finalize_kernel(const float* __restrict__ ncsp, const float* __restrict__ lossp,
                                   float* __restrict__ nout, float* __restrict__ out) {
    __shared__ float r4[4];
    int t = threadIdx.x;
    float ls = (lossp[t] + lossp[t + 256]) + (lossp[t + 512] + lossp[t + 768]);
#pragma unroll
    for (int o = 32; o > 0; o >>= 1) ls += __shfl_down(ls, o, 64);
    if ((t & 63) == 0) r4[t >> 6] = ls;
    __syncthreads();
    if (t == 0) {
        float total = (r4[0] + r4[1]) + (r4[2] + r4[3]);
        out[OUT_LOSS] = 0.25f * (total * (1.0f / 4194304.0f));
    }
    if (t < 64) {
        float nv = (t < 32) ? ncsp[t] : 0.f;
#pragma unroll
        for (int o = 32; o > 0; o >>= 1) nv += __shfl_down(nv, o, 64);
        if (t == 0) nout[0] = nv;
    }
}

// new_ema_embedding + new_embedding
__global__ void vq_embupd_kernel(const float* __restrict__ ema_emb, const float* __restrict__ dw,
                                 const float* __restrict__ ncs_out, const float* __restrict__ nptr,
                                 float* __restrict__ out) {
    int i = blockIdx.x * 256 + threadIdx.x;
    int k = i >> 6;
    float nev = ema_emb[i] * 0.99f + dw[i] * 0.01f;
    out[OUT_NEMA + i] = nev;
    float n = nptr[0];
    float ncs = ncs_out[k];
    float cs = (ncs + 1e-5f) / (n + 8192.0f * 1e-5f) * n;
    out[OUT_NEMB + i] = nev / cs;
}

extern "C" void kernel_launch(void* const* d_in, const int* in_sizes, int n_in,
                              void* d_out, int out_size, void* d_ws, size_t ws_size,
                              hipStream_t stream) {
    (void)in_sizes; (void)n_in; (void)out_size; (void)ws_size;
    const float* z       = (const float*)d_in[0];
    const float* emb     = (const float*)d_in[1];
    const float* ema_cs  = (const float*)d_in[2];
    const float* ema_emb = (const float*)d_in[3];
    float* out = (float*)d_out;
    float* ws  = (float*)d_ws;

    short* eh          = (short*)(ws + WS_EH);                     // aliases dw region
    unsigned short* cm = (unsigned short*)(out + OUT_ZQ);          // aliases z_q region

    vq_ebias_kernel<<<NCODES / 256, 256, 0, stream>>>(emb, ws + WS_EBIAS);
    vq_eprep_kernel<<<(NCODES * DIM / 2) / 256, 256, 0, stream>>>(emb, eh);
    vq_phaseA<<<1024, 256, 0, stream>>>(z, eh, cm);
    // eh dead now; zero counts + lossp + dw (one contiguous range) before phase B
    hipMemsetAsync(ws + WS_COUNTS, 0,
                   (size_t)(WS_DW + NCODES * DIM - WS_COUNTS) * sizeof(float), stream);
    vq_phaseB<<<1024, 512, 0, stream>>>(z, emb, ws + WS_EBIAS,
                                        out, ws + WS_COUNTS, ws + WS_DW, ws + WS_LOSSP);
    vq_ncs_kernel<<<NCODES / 256, 256, 0, stream>>>(ema_cs, ws + WS_COUNTS, out, ws + WS_NCSP);
    vq_finalize_kernel<<<1, 256, 0, stream>>>(ws + WS_NCSP, ws + WS_LOSSP, ws + WS_N, out);
    vq_embupd_kernel<<<(NCODES * DIM) / 256, 256, 0, stream>>>(ema_emb, ws + WS_DW,
                                                               out + OUT_NCS, ws + WS_N, out);
}

// Round 10
// 468.841 us; speedup vs baseline: 1.4901x; 1.3249x over previous
//
#include <hip/hip_runtime.h>
#include <hip/hip_bf16.h>

#define NCODES 8192
#define DIM    64
#define NROWS  65536   // 16*4096

typedef __attribute__((ext_vector_type(8))) short short8v;
typedef __attribute__((ext_vector_type(4))) float f32x4;

// ---- workspace layout (float offsets). Total 541729 f32 ~= 2.17 MB (proven to fit).
#define WS_EBIAS   0         // 8192 f32
#define WS_COUNTS  8192      // 8192 f32
#define WS_LOSSP   16384     // 1024 f32
#define WS_DW      17408     // 524288 f32  (bf16 eh aliases first 1 MB until phaseA done)
#define WS_NCSP    541696    // 32 f32
#define WS_N       541728    // 1 f32
#define WS_END     541729

#define WS_EH      WS_DW     // eh dead after phaseA; dw memset after phaseA

// cm (65536 rows x 128 chunk-max bf16, 16.78 MB) lives in d_out's OUT_ZQ region:
// block b's tile == exactly block b's z_q bytes. Phase B stages tile->LDS, syncs,
// then overwrites with z_q.

// ---- output layout (float offsets, tuple order) ----
#define OUT_ZQ     0
#define OUT_IDX    4194304
#define OUT_LOSS   4259840
#define OUT_NEMB   4259841
#define OUT_NCS    4784129
#define OUT_NEMA   4792321

// embT (f32 transposed codebook, [dq(16)][code(8192)] float4 = 2 MB) lives in the
// OUT_NEMB region (dead until vq_embupd at the end). OUT_NEMB is an odd float
// offset -> pad +3 floats for 16B float4 alignment; the 3-float tail spills into
// OUT_NCS, which is only written AFTER phaseB (by vq_ncs_kernel). Safe by ordering.
#define EMBT_OFF   ((OUT_NEMB + 3) & ~3)

// Screening margin: worst-case bf16(7-bit mantissa) dot error 2*2^-8*||z||max
// ~=0.087 per side + cm quant 0.031 -> 0.236 worst; 0.30 gives 27% headroom.
// (0.15 failed round 5; 0.30 passed rounds 7/8/9.)
#define CUT_MARGIN 0.30f

__device__ __forceinline__ unsigned short f2b(float f) {
    unsigned u = __float_as_uint(f);
    return (unsigned short)((u + 0x7FFFu + ((u >> 16) & 1u)) >> 16);  // RNE
}
__device__ __forceinline__ float b2f(unsigned short h) {
    return __uint_as_float(((unsigned)h) << 16);
}

// ||e_k||^2 per code (f32, used for exact scores in phase B)
__global__ void vq_ebias_kernel(const float* __restrict__ emb, float* __restrict__ ebias) {
    int k = blockIdx.x * 256 + threadIdx.x;
    const float4* e4 = reinterpret_cast<const float4*>(emb + (size_t)k * DIM);
    float s = 0.f;
#pragma unroll
    for (int i = 0; i < 16; i++) {
        float4 v = e4[i];
        s = fmaf(v.x, v.x, s); s = fmaf(v.y, v.y, s);
        s = fmaf(v.z, v.z, s); s = fmaf(v.w, v.w, s);
    }
    ebias[k] = s;
}

// emb f32 -> bf16 (row-major [code][k]) for phase A
__global__ void vq_eprep_kernel(const float* __restrict__ emb, short* __restrict__ eh) {
    int i = blockIdx.x * 256 + threadIdx.x;   // per 2 elems
    float2 v = *reinterpret_cast<const float2*>(emb + (size_t)i * 2);
    unsigned o = (unsigned)f2b(v.x) | ((unsigned)f2b(v.y) << 16);
    *reinterpret_cast<unsigned*>(eh + (size_t)i * 2) = o;
}

// emb f32 -> transposed f32 embT[dq][code] (float4 rows) for phase B recheck.
// Wave = one 64-code chunk; store is 64 consecutive float4 = 1KB coalesced.
__global__ void vq_etrans_kernel(const float* __restrict__ emb, float4* __restrict__ embT) {
    const int wgid = blockIdx.x * 4 + (threadIdx.x >> 6);   // 128 waves
    const int l = threadIdx.x & 63;
    const int code = wgid * 64 + l;
    const float4* er = reinterpret_cast<const float4*>(emb + (size_t)code * 64);
#pragma unroll
    for (int dq = 0; dq < 16; dq++)
        embT[(size_t)dq * NCODES + code] = er[dq];
}

// Phase A: bf16 MFMA screening. Per (row, 64-code chunk) store chunk-max dot (bf16).
// cm layout: [rowblk(1024)][gchunk(128)][row_in_blk(64)] ushort, in OUT_ZQ region.
__global__ __launch_bounds__(256)
void vq_phaseA(const float* __restrict__ z, const short* __restrict__ eh,
               unsigned short* __restrict__ cm)
{
    const int tid = threadIdx.x;
    const int l = tid & 63, w = tid >> 6;
    const int rg = blockIdx.x >> 2;        // 256 row-groups of 256 rows
    const int quarter = blockIdx.x & 3;    // code quarter (2048 codes each)
    const int rowbase = rg * 256 + w * 64; // this wave's 64 rows
    const int kq0 = (l >> 4) * 8;          // lane's k-offset within a K=32 step

    // Loop-invariant B-fragments (z rows, bf16-converted in-register): [rt][kstep]
    short8v B[4][2];
#pragma unroll
    for (int rt = 0; rt < 4; rt++) {
        const float* zr = z + (size_t)(rowbase + rt * 16 + (l & 15)) * 64;
#pragma unroll
        for (int s = 0; s < 2; s++) {
            int k0 = s * 32 + kq0;
            float4 p0 = *reinterpret_cast<const float4*>(zr + k0);
            float4 p1 = *reinterpret_cast<const float4*>(zr + k0 + 4);
            short8v t;
            t[0] = (short)f2b(p0.x); t[1] = (short)f2b(p0.y);
            t[2] = (short)f2b(p0.z); t[3] = (short)f2b(p0.w);
            t[4] = (short)f2b(p1.x); t[5] = (short)f2b(p1.y);
            t[6] = (short)f2b(p1.z); t[7] = (short)f2b(p1.w);
            B[rt][s] = t;
        }
    }

    unsigned short* cmw = cm + (size_t)(rowbase >> 6) * 8192;

    for (int ch = 0; ch < 32; ch++) {
        const int gchunk = quarter * 32 + ch;
        const int cbase = gchunk * 64;
        // A-fragments: 64 codes of this chunk, straight from global (L2-hot)
        short8v A[4][2];
#pragma unroll
        for (int ct = 0; ct < 4; ct++) {
            const short* ep = eh + (size_t)(cbase + ct * 16 + (l & 15)) * 64;
            A[ct][0] = *reinterpret_cast<const short8v*>(ep + kq0);
            A[ct][1] = *reinterpret_cast<const short8v*>(ep + 32 + kq0);
        }
        float runmax[4] = {-3.4e38f, -3.4e38f, -3.4e38f, -3.4e38f};
#pragma unroll
        for (int ct = 0; ct < 4; ct++) {
#pragma unroll
            for (int rt = 0; rt < 4; rt++) {
                f32x4 acc = {0.f, 0.f, 0.f, 0.f};
                acc = __builtin_amdgcn_mfma_f32_16x16x32_bf16(A[ct][0], B[rt][0], acc, 0, 0, 0);
                acc = __builtin_amdgcn_mfma_f32_16x16x32_bf16(A[ct][1], B[rt][1], acc, 0, 0, 0);
                // D col = lane&15 = z row (rt tile); D row = (lane>>4)*4+reg = code
                float m = fmaxf(fmaxf(acc[0], acc[1]), fmaxf(acc[2], acc[3]));
                runmax[rt] = fmaxf(runmax[rt], m);
            }
        }
#pragma unroll
        for (int rt = 0; rt < 4; rt++) {
            float r1 = fmaxf(runmax[rt], __shfl_xor(runmax[rt], 16));
            float r2 = fmaxf(r1, __shfl_xor(r1, 32));
            if (l < 16) cmw[(size_t)gchunk * 64 + rt * 16 + l] = f2b(r2);
        }
    }
}

// Phase B v3: lane = code, transposed-f32 codebook, ZERO inner-loop shuffles.
// Per candidate chunk: 16 independent 1KB-coalesced float4 loads (embT), z row
// hoisted to 16 float4 regs, 4 f32 accumulators -> full exact dot per lane.
// Round-9 postmortem: v2's per-dot 4-step shfl_xor chain + VGPR=20 serialized
// everything (VALU 26%, latency-bound). v3 trades shuffles for register ILP.
__global__ __launch_bounds__(512, 4)
void vq_phaseB(const float* __restrict__ z, const float* __restrict__ emb,
               const float* __restrict__ ebias, const float4* __restrict__ embT,
               float* __restrict__ out, float* __restrict__ counts,
               float* __restrict__ dw, float* __restrict__ lossp)
{
    __shared__ float zlds[64 * 64];
    __shared__ unsigned short cmlds[128][68];
    __shared__ float lred[8];
    const int tid = threadIdx.x;
    const int l = tid & 63, w = tid >> 6;
    const int rowbase = blockIdx.x * 64;

    {   // stage z tile (64 rows x 64 dims f32)
        const float4* zg = reinterpret_cast<const float4*>(z + (size_t)rowbase * 64);
        for (int i = tid; i < 1024; i += 512)
            reinterpret_cast<float4*>(zlds)[i] = zg[i];
    }
    {   // stage this block's cm tile from OUT_ZQ region: [chunk][row]
        const unsigned short* g =
            reinterpret_cast<const unsigned short*>(out + OUT_ZQ) + (size_t)blockIdx.x * 8192;
#pragma unroll
        for (int p = 0; p < 2; p++) {
            int idx = tid + p * 512;                 // ushort8 index 0..1023
            uint4 v = *reinterpret_cast<const uint4*>(g + idx * 8);
            int chunk = idx >> 3, rs = (idx & 7) * 8;
            *reinterpret_cast<uint2*>(&cmlds[chunk][rs])     = make_uint2(v.x, v.y);
            *reinterpret_cast<uint2*>(&cmlds[chunk][rs + 4]) = make_uint2(v.z, v.w);
        }
    }
    __syncthreads();   // cm tile fully in LDS; safe to overwrite with z_q below

    float lacc = 0.f;
    for (int p = 0; p < 8; p++) {
        const int row = w * 8 + p;
        const int grow = rowbase + row;
        float f0 = b2f(cmlds[l][row]);
        float f1 = b2f(cmlds[l + 64][row]);
        float M = fmaxf(f0, f1);
#pragma unroll
        for (int o = 1; o < 64; o <<= 1) M = fmaxf(M, __shfl_xor(M, o));
        const float cut = M - CUT_MARGIN;
        unsigned long long m0 = __ballot(f0 >= cut);
        unsigned long long m1 = __ballot(f1 >= cut);

        // hoist z row into registers (static indices -> stays in VGPRs)
        float4 zv4[16];
#pragma unroll
        for (int q = 0; q < 16; q++)
            zv4[q] = *reinterpret_cast<const float4*>(zlds + row * 64 + q * 4);

        float best = 3.4e38f; int bidx = 0;
        while (m0 | m1) {   // ascending chunk order -> first-occurrence ties
            int c;
            if (m0) { c = __ffsll(m0) - 1; m0 &= m0 - 1; }
            else    { c = 64 + __ffsll(m1) - 1; m1 &= m1 - 1; }
            const int code = c * 64 + l;        // this lane's code
            float d0 = 0.f, d1 = 0.f, d2 = 0.f, d3 = 0.f;
#pragma unroll
            for (int q = 0; q < 4; q++) {
                float4 e0 = embT[(size_t)(4 * q + 0) * NCODES + code];
                float4 e1 = embT[(size_t)(4 * q + 1) * NCODES + code];
                float4 e2 = embT[(size_t)(4 * q + 2) * NCODES + code];
                float4 e3 = embT[(size_t)(4 * q + 3) * NCODES + code];
                d0 = fmaf(e0.x, zv4[4*q+0].x, d0); d0 = fmaf(e0.y, zv4[4*q+0].y, d0);
                d0 = fmaf(e0.z, zv4[4*q+0].z, d0); d0 = fmaf(e0.w, zv4[4*q+0].w, d0);
                d1 = fmaf(e1.x, zv4[4*q+1].x, d1); d1 = fmaf(e1.y, zv4[4*q+1].y, d1);
                d1 = fmaf(e1.z, zv4[4*q+1].z, d1); d1 = fmaf(e1.w, zv4[4*q+1].w, d1);
                d2 = fmaf(e2.x, zv4[4*q+2].x, d2); d2 = fmaf(e2.y, zv4[4*q+2].y, d2);
                d2 = fmaf(e2.z, zv4[4*q+2].z, d2); d2 = fmaf(e2.w, zv4[4*q+2].w, d2);
                d3 = fmaf(e3.x, zv4[4*q+3].x, d3); d3 = fmaf(e3.y, zv4[4*q+3].y, d3);
                d3 = fmaf(e3.z, zv4[4*q+3].z, d3); d3 = fmaf(e3.w, zv4[4*q+3].w, d3);
            }
            float dot = (d0 + d1) + (d2 + d3);
            float s = fmaf(-2.f, dot, ebias[code]);
            if (s < best) { best = s; bidx = code; }   // strict <: earlier chunk wins
        }
        // full 64-lane lexicographic argmin (codes distinct per lane)
#pragma unroll
        for (int o = 1; o < 64; o <<= 1) {
            float ov = __shfl_xor(best, o);
            int oi = __shfl_xor(bidx, o);
            if (ov < best || (ov == best && oi < bidx)) { best = ov; bidx = oi; }
        }
        // fused epilogue: lane = dim
        float ev = emb[(size_t)bidx * 64 + l];
        float zv = zlds[row * 64 + l];
        out[OUT_ZQ + (size_t)grow * 64 + l] = zv + (ev - zv);
        float df = ev - zv;
        lacc = fmaf(df, df, lacc);
        atomicAdd(&dw[(size_t)bidx * 64 + l], zv);
        if (l == 0) {
            out[OUT_IDX + grow] = (float)bidx;
            atomicAdd(&counts[bidx], 1.0f);
        }
    }
#pragma unroll
    for (int o = 1; o < 64; o <<= 1) lacc += __shfl_xor(lacc, o);
    if (l == 0) lred[w] = lacc;
    __syncthreads();
    if (tid == 0) {
        float t = 0.f;
#pragma unroll
        for (int i = 0; i < 8; i++) t += lred[i];
        lossp[blockIdx.x] = t;
    }
}

// new_cluster_size + partial sums
__global__ void vq_ncs_kernel(const float* __restrict__ ema_cs, const float* __restrict__ counts,
                              float* __restrict__ out, float* __restrict__ ncsp) {
    __shared__ float r4[4];
    int k = blockIdx.x * 256 + threadIdx.x;
    float v = ema_cs[k] * 0.99f + counts[k] * 0.01f;
    out[OUT_NCS + k] = v;
    float s = v;
#pragma unroll
    for (int o = 32; o > 0; o >>= 1) s += __shfl_down(s, o, 64);
    if ((threadIdx.x & 63) == 0) r4[threadIdx.x >> 6] = s;
    __syncthreads();
    if (threadIdx.x == 0) ncsp[blockIdx.x] = (r4[0] + r4[1]) + (r4[2] + r4[3]);
}

// n = sum(ncs); vq_loss
__global__ void vq_finalize_kernel(const float* __restrict__ ncsp, const float* __restrict__ lossp,
                                   float* __restrict__ nout, float* __restrict__ out) {
    __shared__ float r4[4];
    int t = threadIdx.x;
    float ls = (lossp[t] + lossp[t + 256]) + (lossp[t + 512] + lossp[t + 768]);
#pragma unroll
    for (int o = 32; o > 0; o >>= 1) ls += __shfl_down(ls, o, 64);
    if ((t & 63) == 0) r4[t >> 6] = ls;
    __syncthreads();
    if (t == 0) {
        float total = (r4[0] + r4[1]) + (r4[2] + r4[3]);
        out[OUT_LOSS] = 0.25f * (total * (1.0f / 4194304.0f));
    }
    if (t < 64) {
        float nv = (t < 32) ? ncsp[t] : 0.f;
#pragma unroll
        for (int o = 32; o > 0; o >>= 1) nv += __shfl_down(nv, o, 64);
        if (t == 0) nout[0] = nv;
    }
}

// new_ema_embedding + new_embedding (overwrites the embT scratch region)
__global__ void vq_embupd_kernel(const float* __restrict__ ema_emb, const float* __restrict__ dw,
                                 const float* __restrict__ ncs_out, const float* __restrict__ nptr,
                                 float* __restrict__ out) {
    int i = blockIdx.x * 256 + threadIdx.x;
    int k = i >> 6;
    float nev = ema_emb[i] * 0.99f + dw[i] * 0.01f;
    out[OUT_NEMA + i] = nev;
    float n = nptr[0];
    float ncs = ncs_out[k];
    float cs = (ncs + 1e-5f) / (n + 8192.0f * 1e-5f) * n;
    out[OUT_NEMB + i] = nev / cs;
}

extern "C" void kernel_launch(void* const* d_in, const int* in_sizes, int n_in,
                              void* d_out, int out_size, void* d_ws, size_t ws_size,
                              hipStream_t stream) {
    (void)in_sizes; (void)n_in; (void)out_size; (void)ws_size;
    const float* z       = (const float*)d_in[0];
    const float* emb     = (const float*)d_in[1];
    const float* ema_cs  = (const float*)d_in[2];
    const float* ema_emb = (const float*)d_in[3];
    float* out = (float*)d_out;
    float* ws  = (float*)d_ws;

    short* eh          = (short*)(ws + WS_EH);                     // aliases dw region
    unsigned short* cm = (unsigned short*)(out + OUT_ZQ);          // aliases z_q region
    float4* embT       = (float4*)(out + EMBT_OFF);                // aliases new_embedding

    vq_ebias_kernel<<<NCODES / 256, 256, 0, stream>>>(emb, ws + WS_EBIAS);
    vq_eprep_kernel<<<(NCODES * DIM / 2) / 256, 256, 0, stream>>>(emb, eh);
    vq_etrans_kernel<<<NCODES / 256, 256, 0, stream>>>(emb, embT);
    vq_phaseA<<<1024, 256, 0, stream>>>(z, eh, cm);
    // eh dead now; zero counts + lossp + dw (one contiguous range) before phase B
    hipMemsetAsync(ws + WS_COUNTS, 0,
                   (size_t)(WS_DW + NCODES * DIM - WS_COUNTS) * sizeof(float), stream);
    vq_phaseB<<<1024, 512, 0, stream>>>(z, emb, ws + WS_EBIAS, embT,
                                        out, ws + WS_COUNTS, ws + WS_DW, ws + WS_LOSSP);
    vq_ncs_kernel<<<NCODES / 256, 256, 0, stream>>>(ema_cs, ws + WS_COUNTS, out, ws + WS_NCSP);
    vq_finalize_kernel<<<1, 256, 0, stream>>>(ws + WS_NCSP, ws + WS_LOSSP, ws + WS_N, out);
    vq_embupd_kernel<<<(NCODES * DIM) / 256, 256, 0, stream>>>(ema_emb, ws + WS_DW,
                                                               out + OUT_NCS, ws + WS_N, out);
}

// Round 11
// 449.902 us; speedup vs baseline: 1.5529x; 1.0421x over previous
//
#include <hip/hip_runtime.h>
#include <hip/hip_bf16.h>

#define NCODES 8192
#define DIM    64
#define NROWS  65536   // 16*4096

typedef __attribute__((ext_vector_type(8))) short short8v;
typedef __attribute__((ext_vector_type(4))) float f32x4;

// ---- workspace layout (float offsets). Total 541729 f32 ~= 2.17 MB (proven to fit).
#define WS_EBIAS   0         // 8192 f32
#define WS_COUNTS  8192      // 8192 f32
#define WS_LOSSP   16384     // 1024 f32
#define WS_DW      17408     // 524288 f32  (bf16 ehF aliases first 1 MB until phaseA done)
#define WS_NCSP    541696    // 32 f32
#define WS_N       541728    // 1 f32
#define WS_END     541729

#define WS_EH      WS_DW     // ehF dead after phaseA; dw memset after phaseA

// cm (65536 rows x 128 chunk-max bf16, 16.78 MB) lives in d_out's OUT_ZQ region.
// embT (f32 transposed codebook, 2 MB) lives in OUT_NEMB (dead until vq_embupd).

// ---- output layout (float offsets, tuple order) ----
#define OUT_ZQ     0
#define OUT_IDX    4194304
#define OUT_LOSS   4259840
#define OUT_NEMB   4259841
#define OUT_NCS    4784129
#define OUT_NEMA   4792321

#define EMBT_OFF   ((OUT_NEMB + 3) & ~3)   // +3 pad for float4 align; tail in OUT_NCS
                                           // which is written only after phaseB.

// Screening margin: worst-case bf16 dot error ~0.174 + cm quant 0.062 -> 0.236;
// 0.30 gives 27% headroom. (0.15 failed round 5; 0.30 passed rounds 7-10.)
#define CUT_MARGIN 0.30f

__device__ __forceinline__ unsigned short f2b(float f) {
    unsigned u = __float_as_uint(f);
    return (unsigned short)((u + 0x7FFFu + ((u >> 16) & 1u)) >> 16);  // RNE
}
__device__ __forceinline__ float b2f(unsigned short h) {
    return __uint_as_float(((unsigned)h) << 16);
}

// ||e_k||^2 per code (f32, used for exact scores in phase B)
__global__ void vq_ebias_kernel(const float* __restrict__ emb, float* __restrict__ ebias) {
    int k = blockIdx.x * 256 + threadIdx.x;
    const float4* e4 = reinterpret_cast<const float4*>(emb + (size_t)k * DIM);
    float s = 0.f;
#pragma unroll
    for (int i = 0; i < 16; i++) {
        float4 v = e4[i];
        s = fmaf(v.x, v.x, s); s = fmaf(v.y, v.y, s);
        s = fmaf(v.z, v.z, s); s = fmaf(v.w, v.w, s);
    }
    ebias[k] = s;
}

// emb f32 -> bf16 in MFMA-FRAGMENT ORDER (r11): ehF[(chunk,ct,s,lane)] = short8 at
// emb[code = chunk*64+ct*16+(lane&15)][k = s*32+(lane>>4)*8 .. +8]. Phase A's
// A-fragment loads then read 64 consecutive short8s = 1KB contiguous per inst
// (was 16-row-strided 16B pieces = 2x the TA line-lookup floor).
__global__ void vq_eprep_kernel(const float* __restrict__ emb, short* __restrict__ ehF) {
    int o = blockIdx.x * 256 + threadIdx.x;   // short8 index, 65536 total
    int l = o & 63;
    int s = (o >> 6) & 1;
    int ct = (o >> 7) & 3;
    int chunk = o >> 9;
    int code = chunk * 64 + ct * 16 + (l & 15);
    int k = s * 32 + (l >> 4) * 8;
    const float4* er = reinterpret_cast<const float4*>(emb + (size_t)code * 64 + k);
    float4 p0 = er[0], p1 = er[1];
    short8v t;
    t[0] = (short)f2b(p0.x); t[1] = (short)f2b(p0.y);
    t[2] = (short)f2b(p0.z); t[3] = (short)f2b(p0.w);
    t[4] = (short)f2b(p1.x); t[5] = (short)f2b(p1.y);
    t[6] = (short)f2b(p1.z); t[7] = (short)f2b(p1.w);
    *reinterpret_cast<short8v*>(ehF + (size_t)o * 8) = t;
}

// emb f32 -> transposed f32 embT[dq][code] (float4 rows) for phase B recheck.
__global__ void vq_etrans_kernel(const float* __restrict__ emb, float4* __restrict__ embT) {
    const int wgid = blockIdx.x * 4 + (threadIdx.x >> 6);
    const int l = threadIdx.x & 63;
    const int code = wgid * 64 + l;
    const float4* er = reinterpret_cast<const float4*>(emb + (size_t)code * 64);
#pragma unroll
    for (int dq = 0; dq < 16; dq++)
        embT[(size_t)dq * NCODES + code] = er[dq];
}

// Phase A: bf16 MFMA screening. Per (row, 64-code chunk) store chunk-max dot (bf16).
// cm layout: [rowblk(1024)][gchunk(128)][row_in_blk(64)] ushort, in OUT_ZQ region.
__global__ __launch_bounds__(256)
void vq_phaseA(const float* __restrict__ z, const short* __restrict__ ehF,
               unsigned short* __restrict__ cm)
{
    const int tid = threadIdx.x;
    const int l = tid & 63, w = tid >> 6;
    const int rg = blockIdx.x >> 2;        // 256 row-groups of 256 rows
    const int quarter = blockIdx.x & 3;    // code quarter (2048 codes each)
    const int rowbase = rg * 256 + w * 64; // this wave's 64 rows
    const int kq0 = (l >> 4) * 8;          // lane's k-offset within a K=32 step

    // Loop-invariant B-fragments (z rows, bf16-converted in-register): [rt][kstep]
    short8v B[4][2];
#pragma unroll
    for (int rt = 0; rt < 4; rt++) {
        const float* zr = z + (size_t)(rowbase + rt * 16 + (l & 15)) * 64;
#pragma unroll
        for (int s = 0; s < 2; s++) {
            int k0 = s * 32 + kq0;
            float4 p0 = *reinterpret_cast<const float4*>(zr + k0);
            float4 p1 = *reinterpret_cast<const float4*>(zr + k0 + 4);
            short8v t;
            t[0] = (short)f2b(p0.x); t[1] = (short)f2b(p0.y);
            t[2] = (short)f2b(p0.z); t[3] = (short)f2b(p0.w);
            t[4] = (short)f2b(p1.x); t[5] = (short)f2b(p1.y);
            t[6] = (short)f2b(p1.z); t[7] = (short)f2b(p1.w);
            B[rt][s] = t;
        }
    }

    unsigned short* cmw = cm + (size_t)(rowbase >> 6) * 8192;
    const short8v* ef = reinterpret_cast<const short8v*>(ehF);

    for (int ch = 0; ch < 32; ch++) {
        const int gchunk = quarter * 32 + ch;
        // A-fragments: fragment-ordered, 1KB-contiguous per load
        const size_t fbase = (size_t)gchunk * 512 + l;   // short8 units
        short8v A[4][2];
#pragma unroll
        for (int ct = 0; ct < 4; ct++) {
            A[ct][0] = ef[fbase + (size_t)(ct * 2 + 0) * 64];
            A[ct][1] = ef[fbase + (size_t)(ct * 2 + 1) * 64];
        }
        float runmax[4] = {-3.4e38f, -3.4e38f, -3.4e38f, -3.4e38f};
#pragma unroll
        for (int ct = 0; ct < 4; ct++) {
#pragma unroll
            for (int rt = 0; rt < 4; rt++) {
                f32x4 acc = {0.f, 0.f, 0.f, 0.f};
                acc = __builtin_amdgcn_mfma_f32_16x16x32_bf16(A[ct][0], B[rt][0], acc, 0, 0, 0);
                acc = __builtin_amdgcn_mfma_f32_16x16x32_bf16(A[ct][1], B[rt][1], acc, 0, 0, 0);
                // D col = lane&15 = z row (rt tile); D row = (lane>>4)*4+reg = code
                float m = fmaxf(fmaxf(acc[0], acc[1]), fmaxf(acc[2], acc[3]));
                runmax[rt] = fmaxf(runmax[rt], m);
            }
        }
#pragma unroll
        for (int rt = 0; rt < 4; rt++) {
            float r1 = fmaxf(runmax[rt], __shfl_xor(runmax[rt], 16));
            float r2 = fmaxf(r1, __shfl_xor(r1, 32));
            if (l < 16) cmw[(size_t)gchunk * 64 + rt * 16 + l] = f2b(r2);
        }
    }
}

// Phase B v4: lane = code, transposed-f32 codebook. All 16 e-loads of a candidate
// issued into NAMED registers before any FMA (one latency exposure per candidate,
// was ~4 serialized groups at VGPR=60). z quads read from LDS in the FMA chain.
// Accumulation grouping identical to v3 (d_j += e_{4q+j} . zquad_{4q+j}).
__global__ __launch_bounds__(512, 4)
void vq_phaseB(const float* __restrict__ z, const float* __restrict__ emb,
               const float* __restrict__ ebias, const float4* __restrict__ embT,
               float* __restrict__ out, float* __restrict__ counts,
               float* __restrict__ dw, float* __restrict__ lossp)
{
    __shared__ float zlds[64 * 64];
    __shared__ unsigned short cmlds[128][68];
    __shared__ float lred[8];
    const int tid = threadIdx.x;
    const int l = tid & 63, w = tid >> 6;
    const int rowbase = blockIdx.x * 64;

    {   // stage z tile (64 rows x 64 dims f32)
        const float4* zg = reinterpret_cast<const float4*>(z + (size_t)rowbase * 64);
        for (int i = tid; i < 1024; i += 512)
            reinterpret_cast<float4*>(zlds)[i] = zg[i];
    }
    {   // stage this block's cm tile from OUT_ZQ region: [chunk][row]
        const unsigned short* g =
            reinterpret_cast<const unsigned short*>(out + OUT_ZQ) + (size_t)blockIdx.x * 8192;
#pragma unroll
        for (int p = 0; p < 2; p++) {
            int idx = tid + p * 512;                 // ushort8 index 0..1023
            uint4 v = *reinterpret_cast<const uint4*>(g + idx * 8);
            int chunk = idx >> 3, rs = (idx & 7) * 8;
            *reinterpret_cast<uint2*>(&cmlds[chunk][rs])     = make_uint2(v.x, v.y);
            *reinterpret_cast<uint2*>(&cmlds[chunk][rs + 4]) = make_uint2(v.z, v.w);
        }
    }
    __syncthreads();   // cm tile fully in LDS; safe to overwrite with z_q below

    float lacc = 0.f;
    for (int p = 0; p < 8; p++) {
        const int row = w * 8 + p;
        const int grow = rowbase + row;
        float f0 = b2f(cmlds[l][row]);
        float f1 = b2f(cmlds[l + 64][row]);
        float M = fmaxf(f0, f1);
#pragma unroll
        for (int o = 1; o < 64; o <<= 1) M = fmaxf(M, __shfl_xor(M, o));
        const float cut = M - CUT_MARGIN;
        unsigned long long m0 = __ballot(f0 >= cut);
        unsigned long long m1 = __ballot(f1 >= cut);

        const float4* zq4 = reinterpret_cast<const float4*>(zlds + (size_t)row * 64);

        float best = 3.4e38f; int bidx = 0;
        while (m0 | m1) {   // ascending chunk order -> first-occurrence ties
            int c;
            if (m0) { c = __ffsll(m0) - 1; m0 &= m0 - 1; }
            else    { c = 64 + __ffsll(m1) - 1; m1 &= m1 - 1; }
            const int code = c * 64 + l;        // this lane's code
            const float4* eb = embT + code;
            // ---- issue ALL 16 loads first (independent, 64 VGPR) ----
            float4 e0  = eb[ 0 * NCODES], e1  = eb[ 1 * NCODES];
            float4 e2  = eb[ 2 * NCODES], e3  = eb[ 3 * NCODES];
            float4 e4  = eb[ 4 * NCODES], e5  = eb[ 5 * NCODES];
            float4 e6  = eb[ 6 * NCODES], e7  = eb[ 7 * NCODES];
            float4 e8  = eb[ 8 * NCODES], e9  = eb[ 9 * NCODES];
            float4 e10 = eb[10 * NCODES], e11 = eb[11 * NCODES];
            float4 e12 = eb[12 * NCODES], e13 = eb[13 * NCODES];
            float4 e14 = eb[14 * NCODES], e15 = eb[15 * NCODES];
            float d0 = 0.f, d1 = 0.f, d2 = 0.f, d3 = 0.f;
#define DOTQ(acc, ev, q) { float4 zv = zq4[q];                          \
            acc = fmaf(ev.x, zv.x, acc); acc = fmaf(ev.y, zv.y, acc);   \
            acc = fmaf(ev.z, zv.z, acc); acc = fmaf(ev.w, zv.w, acc); }
            DOTQ(d0, e0,  0)  DOTQ(d1, e1,  1)  DOTQ(d2, e2,  2)  DOTQ(d3, e3,  3)
            DOTQ(d0, e4,  4)  DOTQ(d1, e5,  5)  DOTQ(d2, e6,  6)  DOTQ(d3, e7,  7)
            DOTQ(d0, e8,  8)  DOTQ(d1, e9,  9)  DOTQ(d2, e10, 10) DOTQ(d3, e11, 11)
            DOTQ(d0, e12, 12) DOTQ(d1, e13, 13) DOTQ(d2, e14, 14) DOTQ(d3, e15, 15)
#undef DOTQ
            float dot = (d0 + d1) + (d2 + d3);
            float s = fmaf(-2.f, dot, ebias[code]);
            if (s < best) { best = s; bidx = code; }   // strict <: earlier chunk wins
        }
        // full 64-lane lexicographic argmin (codes distinct per lane)
#pragma unroll
        for (int o = 1; o < 64; o <<= 1) {
            float ov = __shfl_xor(best, o);
            int oi = __shfl_xor(bidx, o);
            if (ov < best || (ov == best && oi < bidx)) { best = ov; bidx = oi; }
        }
        // fused epilogue: lane = dim
        float ev = emb[(size_t)bidx * 64 + l];
        float zv = zlds[row * 64 + l];
        out[OUT_ZQ + (size_t)grow * 64 + l] = zv + (ev - zv);
        float df = ev - zv;
        lacc = fmaf(df, df, lacc);
        atomicAdd(&dw[(size_t)bidx * 64 + l], zv);
        if (l == 0) {
            out[OUT_IDX + grow] = (float)bidx;
            atomicAdd(&counts[bidx], 1.0f);
        }
    }
#pragma unroll
    for (int o = 1; o < 64; o <<= 1) lacc += __shfl_xor(lacc, o);
    if (l == 0) lred[w] = lacc;
    __syncthreads();
    if (tid == 0) {
        float t = 0.f;
#pragma unroll
        for (int i = 0; i < 8; i++) t += lred[i];
        lossp[blockIdx.x] = t;
    }
}

// new_cluster_size + partial sums
__global__ void vq_ncs_kernel(const float* __restrict__ ema_cs, const float* __restrict__ counts,
                              float* __restrict__ out, float* __restrict__ ncsp) {
    __shared__ float r4[4];
    int k = blockIdx.x * 256 + threadIdx.x;
    float v = ema_cs[k] * 0.99f + counts[k] * 0.01f;
    out[OUT_NCS + k] = v;
    float s = v;
#pragma unroll
    for (int o = 32; o > 0; o >>= 1) s += __shfl_down(s, o, 64);
    if ((threadIdx.x & 63) == 0) r4[threadIdx.x >> 6] = s;
    __syncthreads();
    if (threadIdx.x == 0) ncsp[blockIdx.x] = (r4[0] + r4[1]) + (r4[2] + r4[3]);
}

// n = sum(ncs); vq_loss
__global__ void vq_finalize_kernel(const float* __restrict__ ncsp, const float* __restrict__ lossp,
                                   float* __restrict__ nout, float* __restrict__ out) {
    __shared__ float r4[4];
    int t = threadIdx.x;
    float ls = (lossp[t] + lossp[t + 256]) + (lossp[t + 512] + lossp[t + 768]);
#pragma unroll
    for (int o = 32; o > 0; o >>= 1) ls += __shfl_down(ls, o, 64);
    if ((t & 63) == 0) r4[t >> 6] = ls;
    __syncthreads();
    if (t == 0) {
        float total = (r4[0] + r4[1]) + (r4[2] + r4[3]);
        out[OUT_LOSS] = 0.25f * (total * (1.0f / 4194304.0f));
    }
    if (t < 64) {
        float nv = (t < 32) ? ncsp[t] : 0.f;
#pragma unroll
        for (int o = 32; o > 0; o >>= 1) nv += __shfl_down(nv, o, 64);
        if (t == 0) nout[0] = nv;
    }
}

// new_ema_embedding + new_embedding (overwrites the embT scratch region)
__global__ void vq_embupd_kernel(const float* __restrict__ ema_emb, const float* __restrict__ dw,
                                 const float* __restrict__ ncs_out, const float* __restrict__ nptr,
                                 float* __restrict__ out) {
    int i = blockIdx.x * 256 + threadIdx.x;
    int k = i >> 6;
    float nev = ema_emb[i] * 0.99f + dw[i] * 0.01f;
    out[OUT_NEMA + i] = nev;
    float n = nptr[0];
    float ncs = ncs_out[k];
    float cs = (ncs + 1e-5f) / (n + 8192.0f * 1e-5f) * n;
    out[OUT_NEMB + i] = nev / cs;
}

extern "C" void kernel_launch(void* const* d_in, const int* in_sizes, int n_in,
                              void* d_out, int out_size, void* d_ws, size_t ws_size,
                              hipStream_t stream) {
    (void)in_sizes; (void)n_in; (void)out_size; (void)ws_size;
    const float* z       = (const float*)d_in[0];
    const float* emb     = (const float*)d_in[1];
    const float* ema_cs  = (const float*)d_in[2];
    const float* ema_emb = (const float*)d_in[3];
    float* out = (float*)d_out;
    float* ws  = (float*)d_ws;

    short* ehF         = (short*)(ws + WS_EH);                     // aliases dw region
    unsigned short* cm = (unsigned short*)(out + OUT_ZQ);          // aliases z_q region
    float4* embT       = (float4*)(out + EMBT_OFF);                // aliases new_embedding

    vq_ebias_kernel<<<NCODES / 256, 256, 0, stream>>>(emb, ws + WS_EBIAS);
    vq_eprep_kernel<<<(NCODES * DIM / 8) / 256, 256, 0, stream>>>(emb, ehF);
    vq_etrans_kernel<<<NCODES / 256, 256, 0, stream>>>(emb, embT);
    vq_phaseA<<<1024, 256, 0, stream>>>(z, ehF, cm);
    // ehF dead now; zero counts + lossp + dw (one contiguous range) before phase B
    hipMemsetAsync(ws + WS_COUNTS, 0,
                   (size_t)(WS_DW + NCODES * DIM - WS_COUNTS) * sizeof(float), stream);
    vq_phaseB<<<1024, 512, 0, stream>>>(z, emb, ws + WS_EBIAS, embT,
                                        out, ws + WS_COUNTS, ws + WS_DW, ws + WS_LOSSP);
    vq_ncs_kernel<<<NCODES / 256, 256, 0, stream>>>(ema_cs, ws + WS_COUNTS, out, ws + WS_NCSP);
    vq_finalize_kernel<<<1, 256, 0, stream>>>(ws + WS_NCSP, ws + WS_LOSSP, ws + WS_N, out);
    vq_embupd_kernel<<<(NCODES * DIM) / 256, 256, 0, stream>>>(ema_emb, ws + WS_DW,
                                                               out + OUT_NCS, ws + WS_N, out);
}